// Round 1
// baseline (3039.758 us; speedup 1.0000x reference)
//
#include <hip/hip_runtime.h>
#include <math.h>

typedef long long i64;

#define EPSF 1e-8f

// ---------------- path metadata ----------------
constexpr int NPATH = 15;
constexpr int PI_[NPATH] = {0,0,1,1,1,1,0,1,1,2,2,2,2,2,2};
constexpr int PF_[NPATH] = {0,1,0,1,1,1,2,2,2,2,2,2,0,1,1};
constexpr int PO_[NPATH] = {0,1,1,0,1,2,2,1,2,0,1,2,2,1,2};
constexpr int ISZ[NPATH] = {1,1,3,3,3,3,1,3,3,5,5,5,5,5,5};
constexpr int FSZ[NPATH] = {1,3,1,3,3,3,5,5,5,5,5,5,1,3,3};
constexpr int OSZ[NPATH] = {1,3,3,1,3,5,5,3,5,1,3,5,5,3,5};
constexpr int IBASE[NPATH] = {0,0,1,1,1,1,0,1,1,4,4,4,4,4,4};
constexpr int FBASE[NPATH] = {0,1,0,1,1,1,4,4,4,4,4,4,0,1,1};
constexpr int OBASE[NPATH] = {0,1,1,0,1,4,4,1,4,0,1,4,4,1,4};
constexpr int CGOFF[NPATH+1] = {0,1,10,19,28,55,100,125,170,245,270,345,470,495,540,615};
constexpr int GOFF[NPATH+1]  = {0,1,4,13,16,25,40,45,54,69,74,89,114,139,154,179};
constexpr int CGTOT = 615;
constexpr int GTOT  = 179;

// ---------------- CG init (device-side, mirrors reference _su2_cg/_q) ----------------
__device__ double dfact(int n){ double r=1.0; for(int i=2;i<=n;++i) r*=(double)i; return r; }

__device__ double su2cg(int j1,int m1,int j2,int m2,int j3,int m3){
  if (m1+m2 != m3) return 0.0;
  int vmin = max(max(-j1+j2+m3, -j1+m1), 0);
  int vmax = min(min(j2+j3+m1, j3-j1+j2), j3+m3);
  if (vmax < vmin) return 0.0;
  double c = sqrt((double)(2*j3+1) * dfact(j3+j1-j2)*dfact(j3-j1+j2)*dfact(j1+j2-j3)
                  * dfact(j3+m3)*dfact(j3-m3)
                  / (dfact(j1+j2+j3+1)*dfact(j1-m1)*dfact(j1+m1)*dfact(j2-m2)*dfact(j2+m2)));
  double s = 0.0;
  for (int v=vmin; v<=vmax; ++v){
    double t = dfact(j2+j3+m1-v)*dfact(j1-m1+v)
             / (dfact(v)*dfact(j3-j1+j2-v)*dfact(j3+m3-v)*dfact(j1-j2-m3+v));
    s += ((v+j2+m2)&1) ? -t : t;
  }
  return c*s;
}

__device__ void qmat_lds(int l, double* qr, double* qi){ // 25 doubles each, stride 5
  for (int e=0;e<25;e++){ qr[e]=0.0; qi[e]=0.0; }
  const double s2 = 0.70710678118654752440;
  for (int m=-l; m<0; ++m){
    qr[(l+m)*5 + (l-m)] = s2;     // 1/sqrt2 at col l+|m|
    qi[(l+m)*5 + (l+m)] = -s2;    // -i/sqrt2 at col l-|m|
  }
  qr[l*5+l] = 1.0;
  for (int m=1; m<=l; ++m){
    double sg = (m&1)? -1.0 : 1.0;
    qr[(l+m)*5 + (l+m)] = sg*s2;
    qi[(l+m)*5 + (l-m)] = sg*s2;  // i*(-1)^m/sqrt2
  }
  if (l==1){        // multiply by (-i): (re+i im)*(-i) = im - i re
    for (int e=0;e<25;e++){ double r=qr[e], m=qi[e]; qr[e]=m; qi[e]=-r; }
  } else if (l==2){ // multiply by (-i)^2 = -1
    for (int e=0;e<25;e++){ qr[e]=-qr[e]; qi[e]=-qi[e]; }
  }
}

__global__ void cg_init_kernel(float* __restrict__ cg){
  int p = blockIdx.x;
  int li = PI_[p], lf = PF_[p], lo = PO_[p];
  int isz = 2*li+1, fsz = 2*lf+1, osz = 2*lo+1;
  __shared__ double sC[125];
  __shared__ double qir[25],qii[25],qfr[25],qfi[25],qor[25],qoi[25];
  if (threadIdx.x==0){
    qmat_lds(li,qir,qii); qmat_lds(lf,qfr,qfi); qmat_lds(lo,qor,qoi);
  }
  int tot = isz*fsz*osz;
  for (int e=threadIdx.x; e<tot; e+=blockDim.x){
    int a = e/(fsz*osz); int r = e%(fsz*osz); int b = r/osz; int n = r%osz;
    sC[e] = su2cg(li, a-li, lf, b-lf, lo, n-lo);
  }
  __syncthreads();
  for (int e=threadIdx.x; e<tot; e+=blockDim.x){
    int mo = e/(isz*fsz); int r = e%(isz*fsz); int ji = r/fsz; int lff = r%fsz;
    double acc = 0.0;
    for (int a=0;a<isz;a++) for(int b=0;b<fsz;b++) for(int n=0;n<osz;n++){
      double s = sC[(a*fsz+b)*osz+n];
      if (s==0.0) continue;
      double r1=qir[a*5+ji],  m1=qii[a*5+ji];
      double r2=qfr[b*5+lff], m2=qfi[b*5+lff];
      double r3=qor[n*5+mo],  m3=-qoi[n*5+mo];     // conj
      double rr = r1*r2 - m1*m2;
      double mm = r1*m2 + m1*r2;
      acc += (rr*r3 - mm*m3)*s;
    }
    cg[CGOFF[p] + (mo*isz+ji)*fsz + lff] = (float)acc;
  }
}

// ---------------- helpers ----------------
__device__ __forceinline__ float sspf(float x){  // softplus(x) - ln2
  float sp = (x > 20.f) ? x : log1pf(__expf(x));
  return sp - 0.69314718055994531f;
}

// ---------------- layer-1 self-interaction (one-hot input) ----------------
__global__ void siA1_kernel(const int* __restrict__ types, const float* __restrict__ w,
                            const float* __restrict__ b, float* __restrict__ Vp, int N){
  int idx = blockIdx.x*blockDim.x + threadIdx.x;  // over N*24
  if (idx >= N*24) return;
  int n = idx/24, d = idx%24;
  float v = w[d*3 + types[n]] + b[d];
  float* row = Vp + (i64)idx*12;
  row[0] = v;
  #pragma unroll
  for (int m=1;m<12;m++) row[m]=0.f;
}

// ---------------- conv (the heavy kernel) ----------------
// thread t -> (a = atom-in-block, rks = k-sub-slot, c = channel); per chunk of KS
// neighbor k's, stage rbf/Y -> h -> (G = CG . Y) in LDS, then each (a,c,k) thread
// does r = w2.h and acc[o_m] += r * sum_i G[o_m,i_m]*Vg[i_m].
template<int C, int A, int KS, int T, bool SR>
__global__ __launch_bounds__(T) void conv_kernel(
    const float* __restrict__ Vp, const int* __restrict__ nei_idx,
    const float* __restrict__ nei_vec,
    const float* __restrict__ rw1, const float* __restrict__ rb1,
    const float* __restrict__ rw2, const float* __restrict__ rb2,
    const float* __restrict__ cg, float* __restrict__ O, int N)
{
  constexpr int AK = A*KS;
  static_assert(T == A*C*KS, "bad geometry");
  __shared__ float sw1[15*144];
  __shared__ float sb1[180];
  __shared__ float sw2[15*C*12];
  __shared__ float sb2[15*C];
  __shared__ float sCG[CGTOT];
  __shared__ int   snei[A*32];
  __shared__ float srbf[AK*12];
  __shared__ float sY[AK*9];
  __shared__ float sbuf1[AK*180];           // h; (SR: then G); (KS>1: then reduce buf)
  __shared__ float sr[SR ? AK*15*C : 1];
  __shared__ float sG[SR ? 1 : AK*GTOT];

  const int t = threadIdx.x;
  const int a   = t/(C*KS);
  const int rks = (t%(C*KS))/C;
  const int c   = t%C;
  const int ak  = a*KS + rks;
  const i64 atom0 = (i64)blockIdx.x * A;

  for (int e=t; e<15*144; e+=T) sw1[e]=rw1[e];
  for (int e=t; e<180;    e+=T) sb1[e]=rb1[e];
  for (int e=t; e<15*C*12;e+=T) sw2[e]=rw2[e];
  for (int e=t; e<15*C;   e+=T) sb2[e]=rb2[e];
  for (int e=t; e<CGTOT;  e+=T) sCG[e]=cg[e];
  for (int e=t; e<A*32;   e+=T){
    int aa=e>>5, kk=e&31;
    i64 at=atom0+aa;
    snei[e] = (at<(i64)N) ? nei_idx[at*32+kk] : 0;
  }
  __syncthreads();

  float acc[9];
  #pragma unroll
  for (int m=0;m<9;m++) acc[m]=0.f;

  for (int kc=0; kc<32/KS; ++kc){
    // ---- phase 0: rbf + Y for this chunk ----
    for (int e=t; e<AK; e+=T){
      int aa = e/KS, kss = e%KS;
      int k = kc*KS + kss;
      i64 at = atom0+aa;
      float x=0.f,y=0.f,z=0.f;
      if (at<(i64)N){
        const float* vv = nei_vec + ((i64)at*32 + k)*3;
        x=vv[0]; y=vv[1]; z=vv[2];
      }
      float r2 = fmaxf(x*x+y*y+z*z, EPSF);
      float dist = sqrtf(r2);
      float inv = 1.f/r2;
      float* Ye = &sY[e*9];
      Ye[0]=1.f; Ye[1]=x; Ye[2]=y; Ye[3]=z;
      Ye[4]=x*y*inv;
      Ye[5]=y*z*inv;
      Ye[6]=(2.f*z*z - x*x - y*y)*(0.28867513459481287f*inv);  // 1/(2*sqrt3)
      Ye[7]=z*x*inv;
      Ye[8]=(x*x-y*y)*(0.5f*inv);
      float* Re = &srbf[e*12];
      #pragma unroll
      for (int j=0;j<12;j++){
        float mu = 0.72727272727272727f*(float)j;  // linspace(0,8,12)
        float dd = dist - mu;
        Re[j] = __expf(-dd*dd);
      }
    }
    __syncthreads();
    // ---- phase 1: h = relu(W1 . rbf + b1) ----
    for (int e=t; e<AK*180; e+=T){
      int aa = e/180; int rem = e - aa*180; int p = rem/12; int hd = rem - p*12;
      const float* w  = &sw1[(p*12+hd)*12];
      const float* rb = &srbf[aa*12];
      float v = sb1[p*12+hd];
      #pragma unroll
      for (int j=0;j<12;j++) v += w[j]*rb[j];
      sbuf1[e] = fmaxf(v, 0.f);
    }
    if constexpr (!SR){
      // ---- G = CG . Y (shared across channels) ----
      for (int e=t; e<AK*GTOT; e+=T){
        int aa = e/GTOT; int ge = e - aa*GTOT;
        int p=0;
        #pragma unroll
        for (int q=1;q<NPATH;q++) if (ge >= GOFF[q]) p=q;
        int rel = ge - GOFF[p];
        int fsz = FSZ[p];
        const float* crow = &sCG[CGOFF[p] + rel*fsz];   // (om*isz+im)==rel
        const float* Yr   = &sY[aa*9 + FBASE[p]];
        float v=0.f;
        for (int fm=0; fm<fsz; ++fm) v += crow[fm]*Yr[fm];
        sG[e] = v;
      }
    }
    __syncthreads();
    if constexpr (SR){
      // ---- stage r = W2 . h + b2 (reads h) ----
      for (int e=t; e<AK*15*C; e+=T){
        int aa = e/(15*C); int rem = e - aa*(15*C); int p = rem/C; int cc = rem - p*C;
        const float* w  = &sw2[(p*C+cc)*12];
        const float* hh = &sbuf1[aa*180 + p*12];
        float v = sb2[p*C+cc];
        #pragma unroll
        for (int j=0;j<12;j++) v += w[j]*hh[j];
        sr[e]=v;
      }
      __syncthreads();
      // ---- G into sbuf1 (h is dead now) ----
      for (int e=t; e<AK*GTOT; e+=T){
        int aa = e/GTOT; int ge = e - aa*GTOT;
        int p=0;
        #pragma unroll
        for (int q=1;q<NPATH;q++) if (ge >= GOFF[q]) p=q;
        int rel = ge - GOFF[p];
        int fsz = FSZ[p];
        const float* crow = &sCG[CGOFF[p] + rel*fsz];
        const float* Yr   = &sY[aa*9 + FBASE[p]];
        float v=0.f;
        for (int fm=0; fm<fsz; ++fm) v += crow[fm]*Yr[fm];
        sbuf1[e] = v;
      }
      __syncthreads();
    }
    // ---- inner: per (a, c, k) ----
    {
      int k = kc*KS + rks;
      int nei = snei[a*32 + k];
      const float* vrow = Vp + ((i64)nei*C + c)*12;
      float vg[9];
      float4 v0 = *reinterpret_cast<const float4*>(vrow);
      float4 v1 = *reinterpret_cast<const float4*>(vrow+4);
      vg[0]=v0.x; vg[1]=v0.y; vg[2]=v0.z; vg[3]=v0.w;
      vg[4]=v1.x; vg[5]=v1.y; vg[6]=v1.z; vg[7]=v1.w;
      vg[8]=vrow[8];
      const float* Gak = SR ? &sbuf1[ak*GTOT] : &sG[ak*GTOT];
      #pragma unroll
      for (int p=0;p<NPATH;p++){
        float rr;
        if constexpr (SR){
          rr = sr[ak*(15*C) + p*C + c];
        } else {
          const float* w  = &sw2[(p*C+c)*12];
          const float* hh = &sbuf1[ak*180 + p*12];
          rr = sb2[p*C+c];
          #pragma unroll
          for (int j=0;j<12;j++) rr += w[j]*hh[j];
        }
        const float* Gp = &Gak[GOFF[p]];
        #pragma unroll
        for (int om=0; om<OSZ[p]; ++om){
          float wv = 0.f;
          #pragma unroll
          for (int im=0; im<ISZ[p]; ++im) wv += Gp[om*ISZ[p]+im]*vg[IBASE[p]+im];
          acc[OBASE[p]+om] += rr*wv;
        }
      }
    }
    __syncthreads();
  }

  i64 at = atom0 + a;
  if constexpr (KS==1){
    if (at<(i64)N){
      float* orow = O + ((i64)at*C + c)*12;
      #pragma unroll
      for (int m=0;m<9;m++) orow[m]=acc[m];
    }
  } else {
    __syncthreads();
    float* red = sbuf1;   // reuse (T*9 <= AK*180)
    int slot = (a*C + c)*KS + rks;
    #pragma unroll
    for (int m=0;m<9;m++) red[slot*9+m]=acc[m];
    __syncthreads();
    if (rks==0 && at<(i64)N){
      float* orow = O + ((i64)at*C + c)*12;
      #pragma unroll
      for (int m=0;m<9;m++){
        float s=0.f;
        for (int q=0;q<KS;q++) s += red[((a*C+c)*KS+q)*9+m];
        orow[m]=s;
      }
    }
  }
}

// ---------------- per-atom norm + siB + per-channel global sums ----------------
template<int C>
__global__ __launch_bounds__(64) void normsiB_kernel(
    const float* __restrict__ O, const float* __restrict__ w, const float* __restrict__ b,
    float* __restrict__ Vb, float* __restrict__ gsum, int N)
{
  __shared__ float sW[C*C];
  __shared__ float sO[C*9];
  __shared__ float sg[2*C];
  const int t = threadIdx.x;
  for (int e=t; e<C*C; e+=64) sW[e]=w[e];
  for (int e=t; e<2*C; e+=64) sg[e]=0.f;
  __syncthreads();
  const int iters = (N + gridDim.x - 1)/gridDim.x;
  for (int it=0; it<iters; ++it){
    i64 at = (i64)blockIdx.x + (i64)it*gridDim.x;
    float p0=0.f,p1=0.f,p2=0.f;
    if (at<(i64)N){
      for (int e=t; e<C*9; e+=64){
        int cc=e/9, m=e-cc*9;
        float v = O[((i64)at*C+cc)*12+m];
        sO[e]=v;
        float vv=v*v;
        if (m==0) p0+=vv; else if (m<4) p1+=vv; else p2+=vv;
      }
    }
    #pragma unroll
    for (int off=1; off<64; off<<=1){
      p0 += __shfl_xor(p0, off);
      p1 += __shfl_xor(p1, off);
      p2 += __shfl_xor(p2, off);
    }
    float i0 = 1.f/sqrtf(fmaxf(p0, EPSF));
    float i1 = 1.f/sqrtf(fmaxf(p1, EPSF));
    float i2 = 1.f/sqrtf(fmaxf(p2, EPSF));
    __syncthreads();
    if (at<(i64)N){
      for (int e=t; e<C*9; e+=64){
        int d=e/9, m=e-d*9;
        float inv = (m==0)? i0 : (m<4)? i1 : i2;
        const float* wr = &sW[d*C];
        float s=0.f;
        #pragma unroll
        for (int cc=0; cc<C; ++cc) s += wr[cc]*sO[cc*9+m];
        float outv = s*inv + ((m==0)? b[d] : 0.f);
        Vb[((i64)at*C+d)*12+m]=outv;
        if (m>=1) atomicAdd(&sg[(m<4?0:1)*C + d], outv*outv);
      }
    }
    __syncthreads();
  }
  for (int e=t; e<2*C; e+=64) atomicAdd(&gsum[e], sg[e]);
}

// ---------------- fused nonlinearity + next-layer siA ----------------
template<int Ci, int Co>
__global__ __launch_bounds__(64) void siaNL_kernel(
    const float* __restrict__ Vb, const float* __restrict__ gsum, const float* __restrict__ nlb,
    const float* __restrict__ w, const float* __restrict__ b, float* __restrict__ Vp, int N)
{
  __shared__ float sW[Co*Ci];
  __shared__ float sIn[Ci*9];
  __shared__ float sT[2*Ci];
  const int t=threadIdx.x;
  for (int e=t; e<Co*Ci; e+=64) sW[e]=w[e];
  for (int e=t; e<2*Ci;  e+=64) sT[e] = sqrtf(gsum[e]) + nlb[e];
  __syncthreads();
  const int iters = (N + gridDim.x - 1)/gridDim.x;
  for (int it=0; it<iters; ++it){
    i64 at = (i64)blockIdx.x + (i64)it*gridDim.x;
    if (at<(i64)N){
      for (int e=t; e<Ci*9; e+=64){
        int cc=e/9, m=e-cc*9;
        float v = Vb[((i64)at*Ci+cc)*12+m];
        float x = (m==0)? sspf(v) : (m<4)? v*sT[cc] : v*sT[Ci+cc];
        sIn[e]=x;
      }
    }
    __syncthreads();
    if (at<(i64)N){
      for (int e=t; e<Co*9; e+=64){
        int d=e/9, m=e-d*9;
        const float* wr=&sW[d*Ci];
        float s = (m==0)? b[d] : 0.f;
        #pragma unroll
        for (int cc=0;cc<Ci;++cc) s += wr[cc]*sIn[cc*9+m];
        Vp[((i64)at*Co+d)*12+m]=s;
      }
    }
    __syncthreads();
  }
}

// ---------------- final readout ----------------
__global__ void final_reduce_kernel(const float* __restrict__ Vb, float* __restrict__ Eacc, int N){
  __shared__ float sE[4];
  const int t=threadIdx.x;
  if (t<4) sE[t]=0.f;
  __syncthreads();
  float a0=0.f,a1=0.f,a2=0.f,a3=0.f;
  for (i64 at = (i64)blockIdx.x*blockDim.x + t; at < (i64)N; at += (i64)gridDim.x*blockDim.x){
    const float* row = Vb + at*4*12;
    a0 += sspf(row[0]);  a1 += sspf(row[12]);
    a2 += sspf(row[24]); a3 += sspf(row[36]);
  }
  atomicAdd(&sE[0],a0); atomicAdd(&sE[1],a1);
  atomicAdd(&sE[2],a2); atomicAdd(&sE[3],a3);
  __syncthreads();
  if (t<4) atomicAdd(&Eacc[t], sE[t]);
}

__global__ void final_dense_kernel(const float* __restrict__ Eacc,
    const float* __restrict__ w1,const float* __restrict__ b1,
    const float* __restrict__ w2,const float* __restrict__ b2,
    const float* __restrict__ w3,const float* __restrict__ b3,
    float* __restrict__ out)
{
  __shared__ float sE1[4];
  __shared__ float sH[256];
  const int t=threadIdx.x;
  if (t<4){
    float v=b1[t];
    #pragma unroll
    for (int j=0;j<4;j++) v += w1[t*4+j]*Eacc[j];
    sE1[t] = (v>0.f)? v : expm1f(v);      // elu
  }
  __syncthreads();
  {
    float v=b2[t];
    #pragma unroll
    for (int j=0;j<4;j++) v += w2[t*4+j]*sE1[j];
    sH[t]=v;
  }
  __syncthreads();
  if (t==0){
    float s=b3[0];
    for (int j=0;j<256;j++) s += w3[j]*sH[j];
    out[0]=s;
  }
}

// ---------------- launcher ----------------
extern "C" void kernel_launch(void* const* d_in, const int* in_sizes, int n_in,
                              void* d_out, int out_size, void* d_ws, size_t ws_size,
                              hipStream_t stream)
{
  const int* atom_types = (const int*)d_in[0];
  const int* nei_idx    = (const int*)d_in[1];
  const float* nei_vec  = (const float*)d_in[2];
  const float* in_f[36];
  for (int i=0;i<36 && i<n_in;i++) in_f[i] = (const float*)d_in[i];
  const int N = in_sizes[0];

  const i64 bsz = (i64)N*24*12;                 // padded rows of 12 floats
  const size_t needed = 8192 + (size_t)3*bsz*4;
  if (ws_size < needed) return;                 // fail loud (validation) rather than corrupt

  char* ws = (char*)d_ws;
  float* cg   = (float*)ws;                     // 615 floats
  float* accs = (float*)(ws + 4096);            // gs1[48] gs2[24] gs3[8] Eacc[4]
  float* gs1 = accs; float* gs2 = accs+48; float* gs3 = accs+72; float* Eacc = accs+80;
  float* bufA = (float*)(ws + 8192);
  float* bufB = bufA + bsz;
  float* bufC = bufB + bsz;

  #define LP(l, j) in_f[3 + 9*(l) + (j)]
  hipMemsetAsync(accs, 0, 512, stream);
  cg_init_kernel<<<15, 64, 0, stream>>>(cg);

  // ---- layer 1 (Cin=3 one-hot, C=24) ----
  siA1_kernel<<<(N*24+255)/256, 256, 0, stream>>>(atom_types, LP(0,0), LP(0,1), bufB, N);
  conv_kernel<24,10,1,240,false><<<(N+9)/10, 240, 0, stream>>>(bufB, nei_idx, nei_vec,
      LP(0,2),LP(0,3),LP(0,4),LP(0,5), cg, bufC, N);
  normsiB_kernel<24><<<2048,64,0,stream>>>(bufC, LP(0,6), LP(0,7), bufA, gs1, N);
  // ---- layer 2 (C=12) ----
  siaNL_kernel<24,12><<<2048,64,0,stream>>>(bufA, gs1, LP(0,8), LP(1,0), LP(1,1), bufB, N);
  conv_kernel<12,20,1,240,false><<<(N+19)/20, 240, 0, stream>>>(bufB, nei_idx, nei_vec,
      LP(1,2),LP(1,3),LP(1,4),LP(1,5), cg, bufC, N);
  normsiB_kernel<12><<<2048,64,0,stream>>>(bufC, LP(1,6), LP(1,7), bufA, gs2, N);
  // ---- layer 3 (C=4) ----
  siaNL_kernel<12,4><<<2048,64,0,stream>>>(bufA, gs2, LP(1,8), LP(2,0), LP(2,1), bufB, N);
  conv_kernel<4,16,2,128,true><<<(N+15)/16, 128, 0, stream>>>(bufB, nei_idx, nei_vec,
      LP(2,2),LP(2,3),LP(2,4),LP(2,5), cg, bufC, N);
  normsiB_kernel<4><<<2048,64,0,stream>>>(bufC, LP(2,6), LP(2,7), bufA, gs3, N);
  // ---- readout ----
  final_reduce_kernel<<<128,256,0,stream>>>(bufA, Eacc, N);
  final_dense_kernel<<<1,256,0,stream>>>(Eacc, in_f[30],in_f[31],in_f[32],in_f[33],in_f[34],in_f[35],
                                         (float*)d_out);
  #undef LP
}